// Round 7
// baseline (1779.903 us; speedup 1.0000x reference)
//
#include <hip/hip_runtime.h>
#include <hip/hip_bf16.h>

using short8 = __attribute__((ext_vector_type(8))) short;
using short4v = __attribute__((ext_vector_type(4))) short;
using f32x4 = __attribute__((ext_vector_type(4))) float;

#define MFMA(a, b, c) __builtin_amdgcn_mfma_f32_16x16x32_bf16((a), (b), (c), 0, 0, 0)

// LDS map (bytes), all XOR-swizzled with ^((row&7)<<4) inside each row:
//  [0,     32768)  xb : x bf16 [64 tok][256], rows 512B. Dead after pass-2 QKV
//                       A-frag reads -> reused as ob (O buffer) for proj.
//  [32768, 65536)  qk : per pass [64 tok][q 128 | k 128] bf16, rows 512B.
//                       After B1.5 overlaid by P: [4 head][64 qtok][64 ktok] bf16.
//  [65536, 81920)  vt : per pass [128 dim][64 tok] bf16, rows 128B.
// total 81920B -> 2 blocks/CU (2*81920 = 163840 = full LDS pool; 512B granule).
#define XBOFF 0
#define QKOFF 32768
#define VTOFF 65536
#define LDSBYTES 81920

__global__ void prep_weights(const float* __restrict__ qkv_w, const float* __restrict__ proj_w,
                             __hip_bfloat16* __restrict__ wq_t, __hip_bfloat16* __restrict__ wp_t) {
    int j = blockIdx.x, t = threadIdx.x;
    if (j < 768) {
        wq_t[j * 256 + t] = __float2bfloat16(qkv_w[t * 768 + j]);
    } else {
        int j2 = j - 768;
        wp_t[j2 * 256 + t] = __float2bfloat16(proj_w[t * 256 + j2]);
    }
}

__global__ __launch_bounds__(512, 4) void swin_fused(
    const float* __restrict__ x, const float* __restrict__ mask,
    const float* __restrict__ qkv_b, const float* __restrict__ proj_b,
    const float* __restrict__ rpb,
    const __hip_bfloat16* __restrict__ wq_t, const __hip_bfloat16* __restrict__ wp_t,
    float* __restrict__ out)
{
    __shared__ __align__(16) char lds[LDSBYTES];

    const int tid = threadIdx.x;
    const int wv = tid >> 6;      // wave 0..7
    const int lane = tid & 63;
    const int lg = lane >> 4;     // 0..3
    const int li = lane & 15;     // 0..15
    const int b = blockIdx.x;
    const int w = b & 63;         // window index for mask
    const int hh = wv >> 1;       // head-within-pass 0..3
    const int c16 = wv & 1;       // dim-16 block (QKV phase)
    const int qh = wv & 1;        // q-row half (S/PV phase)

    // ---- phase 1: x -> xb bf16 swizzled (16B per thread per iter) ----
#pragma unroll
    for (int it = 0; it < 4; ++it) {
        int flat = (it * 512 + tid) * 16;      // byte offset in xb
        int row = flat >> 9;
        int colb = flat & 511;                 // bf16-byte col
        const float* xp = x + (size_t)b * 16384 + row * 256 + (colb >> 1);
        float4 v0 = *(const float4*)xp;
        float4 v1 = *(const float4*)(xp + 4);
        __hip_bfloat16 t8[8] = {__float2bfloat16(v0.x), __float2bfloat16(v0.y),
                                __float2bfloat16(v0.z), __float2bfloat16(v0.w),
                                __float2bfloat16(v1.x), __float2bfloat16(v1.y),
                                __float2bfloat16(v1.z), __float2bfloat16(v1.w)};
        *(short8*)(lds + XBOFF + row * 512 + (colb ^ ((row & 7) << 4))) = *(const short8*)t8;
    }
    __syncthreads(); // B0

    // ---- hoisted rel-pos indices (pass/head independent): m = qh*32+m2*16+lg*4+r ----
    unsigned idxp[2][4];
#pragma unroll
    for (int m2 = 0; m2 < 2; ++m2)
#pragma unroll
        for (int nt = 0; nt < 4; ++nt) {
            unsigned pk = 0;
#pragma unroll
            for (int r = 0; r < 4; ++r) {
                int m = qh * 32 + m2 * 16 + lg * 4 + r;
                int n = nt * 16 + li;
                unsigned idx = (unsigned)(((m >> 3) - (n >> 3) + 7) * 15 + ((m & 7) - (n & 7) + 7));
                pk |= idx << (8 * r);
            }
            idxp[m2][nt] = pk;
        }

    const float scale = 0.17677669529663687f; // 32^-0.5, folded into q
    f32x4 o1[2][2]; // pass-1 normalized O, parked until xb is dead

#pragma unroll 1
    for (int p = 0; p < 2; ++p) {
        const int head = p * 4 + hh;

        // ---- QKV: wave owns dim-16 block (hh,c16) of q,k,v for all 64 tokens ----
        f32x4 acc[3][4];
#pragma unroll
        for (int s = 0; s < 3; ++s)
#pragma unroll
            for (int mt = 0; mt < 4; ++mt) acc[s][mt] = (f32x4)0.f;
#pragma unroll
        for (int kt = 0; kt < 8; ++kt) {
            short8 af[4];
#pragma unroll
            for (int mt = 0; mt < 4; ++mt)
                af[mt] = *(const short8*)(lds + XBOFF + (mt * 16 + li) * 512 +
                                          ((kt * 64 + lg * 16) ^ ((li & 7) << 4)));
#pragma unroll
            for (int s = 0; s < 3; ++s) {
                int wcol = s * 256 + head * 32 + c16 * 16 + li;
                short8 bf = *(const short8*)(wq_t + wcol * 256 + kt * 32 + lg * 8);
#pragma unroll
                for (int mt = 0; mt < 4; ++mt) acc[s][mt] = MFMA(af[mt], bf, acc[s][mt]);
            }
        }
        { // epilogue -> qk / vt
            float bq = qkv_b[head * 32 + c16 * 16 + li];
            float bk = qkv_b[256 + head * 32 + c16 * 16 + li];
            float bv = qkv_b[512 + head * 32 + c16 * 16 + li];
            int colq = (hh * 32 + c16 * 16 + li) * 2;
            int dim = hh * 32 + c16 * 16 + li;
#pragma unroll
            for (int mt = 0; mt < 4; ++mt) {
                short4v t4;
#pragma unroll
                for (int r = 0; r < 4; ++r) {
                    int tok = mt * 16 + lg * 4 + r;
                    int sw = (tok & 7) << 4;
                    __hip_bfloat16 tq = __float2bfloat16((acc[0][mt][r] + bq) * scale);
                    __hip_bfloat16 tk = __float2bfloat16(acc[1][mt][r] + bk);
                    *(__hip_bfloat16*)(lds + QKOFF + tok * 512 + (colq ^ sw)) = tq;
                    *(__hip_bfloat16*)(lds + QKOFF + tok * 512 + ((256 + colq) ^ sw)) = tk;
                    __hip_bfloat16 tv = __float2bfloat16(acc[2][mt][r] + bv);
                    t4[r] = *reinterpret_cast<short*>(&tv);
                }
                *(short4v*)(lds + VTOFF + dim * 128 +
                            ((mt * 32 + lg * 8) ^ ((dim & 7) << 4))) = t4;
            }
        }
        __syncthreads(); // B1: qk/vt ready; (p==1: xb now dead everywhere)

        if (p == 1) { // park pass-1 O into ob (= xb region)
#pragma unroll
            for (int m2 = 0; m2 < 2; ++m2)
#pragma unroll
                for (int n2 = 0; n2 < 2; ++n2)
#pragma unroll
                    for (int r = 0; r < 4; ++r) {
                        int tok = qh * 32 + m2 * 16 + lg * 4 + r;
                        int col = (hh * 32 + n2 * 16 + li) * 2; // pass-1 cols 0..127
                        __hip_bfloat16 tb = __float2bfloat16(o1[m2][n2][r]);
                        *(__hip_bfloat16*)(lds + XBOFF + tok * 512 +
                                           (col ^ ((tok & 7) << 4))) = tb;
                    }
        }

        // ---- S = q k^T + bias + mask: wave = (head hh, q-half qh), rows complete ----
        f32x4 s[2][4];
        {
            short8 aq[2];
#pragma unroll
            for (int m2 = 0; m2 < 2; ++m2) {
                int row = qh * 32 + m2 * 16 + li;
                aq[m2] = *(const short8*)(lds + QKOFF + row * 512 +
                                          ((hh * 64 + lg * 16) ^ ((li & 7) << 4)));
            }
#pragma unroll
            for (int nt = 0; nt < 4; ++nt) {
                int row = nt * 16 + li;
                short8 bk = *(const short8*)(lds + QKOFF + row * 512 +
                                             ((256 + hh * 64 + lg * 16) ^ ((li & 7) << 4)));
#pragma unroll
                for (int m2 = 0; m2 < 2; ++m2) s[m2][nt] = MFMA(aq[m2], bk, (f32x4)0.f);
            }
            const float* rpbh = rpb + head;
            const float* mw = mask + w * 4096;
#pragma unroll
            for (int m2 = 0; m2 < 2; ++m2)
#pragma unroll
                for (int nt = 0; nt < 4; ++nt) {
                    int n = nt * 16 + li;
#pragma unroll
                    for (int r = 0; r < 4; ++r) {
                        int m = qh * 32 + m2 * 16 + lg * 4 + r;
                        int idx = (int)((idxp[m2][nt] >> (8 * r)) & 255u);
                        s[m2][nt][r] += rpbh[idx * 8] + mw[m * 64 + n];
                    }
                }
        }
        // softmax (deferred normalization; rinv stays in registers)
        float rinv[2][4];
#pragma unroll
        for (int m2 = 0; m2 < 2; ++m2)
#pragma unroll
            for (int r = 0; r < 4; ++r) {
                float mx = fmaxf(fmaxf(s[m2][0][r], s[m2][1][r]),
                                 fmaxf(s[m2][2][r], s[m2][3][r]));
#pragma unroll
                for (int off = 1; off < 16; off <<= 1) mx = fmaxf(mx, __shfl_xor(mx, off));
                float sum = 0.f;
#pragma unroll
                for (int nt = 0; nt < 4; ++nt) {
                    float pv = __expf(s[m2][nt][r] - mx);
                    s[m2][nt][r] = pv;
                    sum += pv;
                }
#pragma unroll
                for (int off = 1; off < 16; off <<= 1) sum += __shfl_xor(sum, off);
                rinv[m2][r] = 1.f / sum;
            }
        __syncthreads(); // B1.5: all waves' q/k fragment reads done -> P may overlay qk

        // ---- P -> LDS (P[hh] = 8KB at QKOFF + hh*8192) ----
#pragma unroll
        for (int m2 = 0; m2 < 2; ++m2)
#pragma unroll
            for (int r = 0; r < 4; ++r) {
                int qtok = qh * 32 + m2 * 16 + lg * 4 + r;
                int sw = (qtok & 7) << 4;
#pragma unroll
                for (int nt = 0; nt < 4; ++nt) {
                    __hip_bfloat16 tb = __float2bfloat16(s[m2][nt][r]);
                    *(__hip_bfloat16*)(lds + QKOFF + hh * 8192 + qtok * 128 +
                                       (((nt * 16 + li) * 2) ^ sw)) = tb;
                }
            }
        __syncthreads(); // B2: P ready

        // ---- PV: wave = (hh, qh): m2 x n2 tiles, normalize with in-reg rinv ----
        f32x4 o[2][2] = {{(f32x4)0.f, (f32x4)0.f}, {(f32x4)0.f, (f32x4)0.f}};
#pragma unroll
        for (int kth = 0; kth < 2; ++kth) {
            short8 pa[2], vb[2];
#pragma unroll
            for (int m2 = 0; m2 < 2; ++m2) {
                int qtok = qh * 32 + m2 * 16 + li;
                pa[m2] = *(const short8*)(lds + QKOFF + hh * 8192 + qtok * 128 +
                                          ((kth * 64 + lg * 16) ^ ((li & 7) << 4)));
            }
#pragma unroll
            for (int n2 = 0; n2 < 2; ++n2) {
                int dim = hh * 32 + n2 * 16 + li;
                vb[n2] = *(const short8*)(lds + VTOFF + dim * 128 +
                                          ((kth * 64 + lg * 16) ^ ((li & 7) << 4)));
            }
#pragma unroll
            for (int m2 = 0; m2 < 2; ++m2)
#pragma unroll
                for (int n2 = 0; n2 < 2; ++n2) o[m2][n2] = MFMA(pa[m2], vb[n2], o[m2][n2]);
        }
#pragma unroll
        for (int m2 = 0; m2 < 2; ++m2)
#pragma unroll
            for (int n2 = 0; n2 < 2; ++n2)
#pragma unroll
                for (int r = 0; r < 4; ++r) o[m2][n2][r] *= rinv[m2][r];

        if (p == 0) {
#pragma unroll
            for (int m2 = 0; m2 < 2; ++m2)
#pragma unroll
                for (int n2 = 0; n2 < 2; ++n2) o1[m2][n2] = o[m2][n2];
            __syncthreads(); // B3: pass-1 P/vt reads done before pass-2 QKV overwrites
        } else {
            // write pass-2 O -> ob (cols 128..255)
#pragma unroll
            for (int m2 = 0; m2 < 2; ++m2)
#pragma unroll
                for (int n2 = 0; n2 < 2; ++n2)
#pragma unroll
                    for (int r = 0; r < 4; ++r) {
                        int tok = qh * 32 + m2 * 16 + lg * 4 + r;
                        int col = (128 + hh * 32 + n2 * 16 + li) * 2;
                        __hip_bfloat16 tb = __float2bfloat16(o[m2][n2][r]);
                        *(__hip_bfloat16*)(lds + XBOFF + tok * 512 +
                                           (col ^ ((tok & 7) << 4))) = tb;
                    }
        }
    }
    __syncthreads(); // B4: ob complete

    // ---- proj: wave wv -> out cols wv*32 .. +31 ----
    {
        f32x4 po[4][2] = {{(f32x4)0.f, (f32x4)0.f}, {(f32x4)0.f, (f32x4)0.f},
                          {(f32x4)0.f, (f32x4)0.f}, {(f32x4)0.f, (f32x4)0.f}};
#pragma unroll
        for (int kt = 0; kt < 8; ++kt) {
            short8 a[4];
#pragma unroll
            for (int mt = 0; mt < 4; ++mt)
                a[mt] = *(const short8*)(lds + XBOFF + (mt * 16 + li) * 512 +
                                         ((kt * 64 + lg * 16) ^ ((li & 7) << 4)));
#pragma unroll
            for (int n = 0; n < 2; ++n) {
                int col = wv * 32 + n * 16 + li;
                short8 bb = *(const short8*)(wp_t + col * 256 + kt * 32 + lg * 8);
#pragma unroll
                for (int mt = 0; mt < 4; ++mt) po[mt][n] = MFMA(a[mt], bb, po[mt][n]);
            }
        }
        float* op = out + (size_t)b * 16384;
#pragma unroll
        for (int n = 0; n < 2; ++n) {
            int col = wv * 32 + n * 16 + li;
            float pb = proj_b[col];
#pragma unroll
            for (int mt = 0; mt < 4; ++mt)
#pragma unroll
                for (int r = 0; r < 4; ++r)
                    op[(mt * 16 + lg * 4 + r) * 256 + col] = po[mt][n][r] + pb;
        }
    }
}

extern "C" void kernel_launch(void* const* d_in, const int* in_sizes, int n_in,
                              void* d_out, int out_size, void* d_ws, size_t ws_size,
                              hipStream_t stream) {
    const float* x      = (const float*)d_in[0];
    const float* mask   = (const float*)d_in[1];
    const float* qkv_w  = (const float*)d_in[2];
    const float* qkv_b  = (const float*)d_in[3];
    const float* proj_w = (const float*)d_in[4];
    const float* proj_b = (const float*)d_in[5];
    const float* rpb    = (const float*)d_in[6];

    __hip_bfloat16* wq_t = (__hip_bfloat16*)d_ws;          // [768][256] bf16
    __hip_bfloat16* wp_t = wq_t + 768 * 256;               // [256][256] bf16

    prep_weights<<<1024, 256, 0, stream>>>(qkv_w, proj_w, wq_t, wp_t);
    swin_fused<<<4096, 512, 0, stream>>>(x, mask, qkv_b, proj_b, rpb, wq_t, wp_t, (float*)d_out);
}

// Round 8
// 1115.302 us; speedup vs baseline: 1.5959x; 1.5959x over previous
//
#include <hip/hip_runtime.h>
#include <hip/hip_bf16.h>

using short8 = __attribute__((ext_vector_type(8))) short;
using short4v = __attribute__((ext_vector_type(4))) short;
using f32x4 = __attribute__((ext_vector_type(4))) float;

#define MFMA(a, b, c) __builtin_amdgcn_mfma_f32_16x16x32_bf16((a), (b), (c), 0, 0, 0)

// LDS map (bytes), all XOR-swizzled with ^((row&7)<<4) inside each row:
//  [0,     32768)  xb : x bf16 [64 tok][256], rows 512B. Dead after pass-2 QKV
//                       A-frag reads -> reused as ob (O buffer) for proj.
//  [32768, 65536)  qk : per pass [64 tok][q 128 | k 128] bf16, rows 512B.
//                       After B1.5 overlaid by P: [4 head][64 qtok][64 ktok] bf16.
//  [65536, 81920)  vt : per pass [128 dim][64 tok] bf16, rows 128B.
// total 81920B -> 2 blocks/CU. VGPR must stay <=128 for 4 waves/SIMD:
// __launch_bounds__(512,2) => cap 131072/(512*2)=128 (empirical: R1=128, R6/R7 (512,4)=64+spills).
#define XBOFF 0
#define QKOFF 32768
#define VTOFF 65536
#define LDSBYTES 81920

__global__ void prep_weights(const float* __restrict__ qkv_w, const float* __restrict__ proj_w,
                             __hip_bfloat16* __restrict__ wq_t, __hip_bfloat16* __restrict__ wp_t) {
    int j = blockIdx.x, t = threadIdx.x;
    if (j < 768) {
        wq_t[j * 256 + t] = __float2bfloat16(qkv_w[t * 768 + j]);
    } else {
        int j2 = j - 768;
        wp_t[j2 * 256 + t] = __float2bfloat16(proj_w[t * 256 + j2]);
    }
}

__global__ __launch_bounds__(512, 2) void swin_fused(
    const float* __restrict__ x, const float* __restrict__ mask,
    const float* __restrict__ qkv_b, const float* __restrict__ proj_b,
    const float* __restrict__ rpb,
    const __hip_bfloat16* __restrict__ wq_t, const __hip_bfloat16* __restrict__ wp_t,
    float* __restrict__ out)
{
    __shared__ __align__(16) char lds[LDSBYTES];

    const int tid = threadIdx.x;
    const int wv = tid >> 6;      // wave 0..7
    const int lane = tid & 63;
    const int lg = lane >> 4;     // 0..3
    const int li = lane & 15;     // 0..15
    const int b = blockIdx.x;
    const int w = b & 63;         // window index for mask
    const int hh = wv >> 1;       // head-within-pass 0..3
    const int c16 = wv & 1;       // dim-16 block (QKV phase)
    const int qh = wv & 1;        // q-row half (S/PV phase)

    // ---- phase 1: x -> xb bf16 swizzled (16B per thread per iter) ----
#pragma unroll
    for (int it = 0; it < 4; ++it) {
        int flat = (it * 512 + tid) * 16;      // byte offset in xb
        int row = flat >> 9;
        int colb = flat & 511;                 // bf16-byte col
        const float* xp = x + (size_t)b * 16384 + row * 256 + (colb >> 1);
        float4 v0 = *(const float4*)xp;
        float4 v1 = *(const float4*)(xp + 4);
        __hip_bfloat16 t8[8] = {__float2bfloat16(v0.x), __float2bfloat16(v0.y),
                                __float2bfloat16(v0.z), __float2bfloat16(v0.w),
                                __float2bfloat16(v1.x), __float2bfloat16(v1.y),
                                __float2bfloat16(v1.z), __float2bfloat16(v1.w)};
        *(short8*)(lds + XBOFF + row * 512 + (colb ^ ((row & 7) << 4))) = *(const short8*)t8;
    }
    __syncthreads(); // B0

    // ---- hoisted rel-pos indices (pass/head independent): m = qh*32+m2*16+lg*4+r ----
    unsigned idxp[2][4];
#pragma unroll
    for (int m2 = 0; m2 < 2; ++m2)
#pragma unroll
        for (int nt = 0; nt < 4; ++nt) {
            unsigned pk = 0;
#pragma unroll
            for (int r = 0; r < 4; ++r) {
                int m = qh * 32 + m2 * 16 + lg * 4 + r;
                int n = nt * 16 + li;
                unsigned idx = (unsigned)(((m >> 3) - (n >> 3) + 7) * 15 + ((m & 7) - (n & 7) + 7));
                pk |= idx << (8 * r);
            }
            idxp[m2][nt] = pk;
        }

    const float scale = 0.17677669529663687f; // 32^-0.5, folded into q
    unsigned o1u[8]; // pass-1 O parked as packed bf16 pairs (8 VGPRs, not 16)

#pragma unroll 1
    for (int p = 0; p < 2; ++p) {
        const int head = p * 4 + hh;

        // ---- QKV: wave owns dim-16 block (hh,c16) of q,k,v for all 64 tokens ----
        f32x4 acc[3][4];
#pragma unroll
        for (int s = 0; s < 3; ++s)
#pragma unroll
            for (int mt = 0; mt < 4; ++mt) acc[s][mt] = (f32x4)0.f;
#pragma unroll
        for (int kt = 0; kt < 8; ++kt) {
            short8 af[4];
#pragma unroll
            for (int mt = 0; mt < 4; ++mt)
                af[mt] = *(const short8*)(lds + XBOFF + (mt * 16 + li) * 512 +
                                          ((kt * 64 + lg * 16) ^ ((li & 7) << 4)));
#pragma unroll
            for (int s = 0; s < 3; ++s) {
                int wcol = s * 256 + head * 32 + c16 * 16 + li;
                short8 bf = *(const short8*)(wq_t + wcol * 256 + kt * 32 + lg * 8);
#pragma unroll
                for (int mt = 0; mt < 4; ++mt) acc[s][mt] = MFMA(af[mt], bf, acc[s][mt]);
            }
        }
        { // epilogue -> qk / vt
            float bq = qkv_b[head * 32 + c16 * 16 + li];
            float bk = qkv_b[256 + head * 32 + c16 * 16 + li];
            float bv = qkv_b[512 + head * 32 + c16 * 16 + li];
            int colq = (hh * 32 + c16 * 16 + li) * 2;
            int dim = hh * 32 + c16 * 16 + li;
#pragma unroll
            for (int mt = 0; mt < 4; ++mt) {
                short4v t4;
#pragma unroll
                for (int r = 0; r < 4; ++r) {
                    int tok = mt * 16 + lg * 4 + r;
                    int sw = (tok & 7) << 4;
                    __hip_bfloat16 tq = __float2bfloat16((acc[0][mt][r] + bq) * scale);
                    __hip_bfloat16 tk = __float2bfloat16(acc[1][mt][r] + bk);
                    *(__hip_bfloat16*)(lds + QKOFF + tok * 512 + (colq ^ sw)) = tq;
                    *(__hip_bfloat16*)(lds + QKOFF + tok * 512 + ((256 + colq) ^ sw)) = tk;
                    __hip_bfloat16 tv = __float2bfloat16(acc[2][mt][r] + bv);
                    t4[r] = *reinterpret_cast<short*>(&tv);
                }
                *(short4v*)(lds + VTOFF + dim * 128 +
                            ((mt * 32 + lg * 8) ^ ((dim & 7) << 4))) = t4;
            }
        }
        __syncthreads(); // B1: qk/vt ready; (p==1: xb now dead everywhere)

        if (p == 1) { // park pass-1 O (packed bf16) into ob (= xb region), cols 0..127
#pragma unroll
            for (int m2 = 0; m2 < 2; ++m2)
#pragma unroll
                for (int n2 = 0; n2 < 2; ++n2)
#pragma unroll
                    for (int r = 0; r < 4; ++r) {
                        int tok = qh * 32 + m2 * 16 + lg * 4 + r;
                        int col = (hh * 32 + n2 * 16 + li) * 2;
                        unsigned short us = (unsigned short)
                            ((o1u[m2 * 4 + n2 * 2 + (r >> 1)] >> (16 * (r & 1))) & 0xffffu);
                        *(unsigned short*)(lds + XBOFF + tok * 512 +
                                           (col ^ ((tok & 7) << 4))) = us;
                    }
        }

        // ---- S = q k^T + bias + mask: wave = (head hh, q-half qh), rows complete ----
        f32x4 s[2][4];
        {
            short8 aq[2];
#pragma unroll
            for (int m2 = 0; m2 < 2; ++m2) {
                int row = qh * 32 + m2 * 16 + li;
                aq[m2] = *(const short8*)(lds + QKOFF + row * 512 +
                                          ((hh * 64 + lg * 16) ^ ((li & 7) << 4)));
            }
#pragma unroll
            for (int nt = 0; nt < 4; ++nt) {
                int row = nt * 16 + li;
                short8 bk = *(const short8*)(lds + QKOFF + row * 512 +
                                             ((256 + hh * 64 + lg * 16) ^ ((li & 7) << 4)));
#pragma unroll
                for (int m2 = 0; m2 < 2; ++m2) s[m2][nt] = MFMA(aq[m2], bk, (f32x4)0.f);
            }
            const float* rpbh = rpb + head;
            const float* mw = mask + w * 4096;
#pragma unroll
            for (int m2 = 0; m2 < 2; ++m2)
#pragma unroll
                for (int nt = 0; nt < 4; ++nt) {
                    int n = nt * 16 + li;
#pragma unroll
                    for (int r = 0; r < 4; ++r) {
                        int m = qh * 32 + m2 * 16 + lg * 4 + r;
                        int idx = (int)((idxp[m2][nt] >> (8 * r)) & 255u);
                        s[m2][nt][r] += rpbh[idx * 8] + mw[m * 64 + n];
                    }
                }
        }
        // softmax (deferred normalization; rinv stays in registers)
        float rinv[2][4];
#pragma unroll
        for (int m2 = 0; m2 < 2; ++m2)
#pragma unroll
            for (int r = 0; r < 4; ++r) {
                float mx = fmaxf(fmaxf(s[m2][0][r], s[m2][1][r]),
                                 fmaxf(s[m2][2][r], s[m2][3][r]));
#pragma unroll
                for (int off = 1; off < 16; off <<= 1) mx = fmaxf(mx, __shfl_xor(mx, off));
                float sum = 0.f;
#pragma unroll
                for (int nt = 0; nt < 4; ++nt) {
                    float pv = __expf(s[m2][nt][r] - mx);
                    s[m2][nt][r] = pv;
                    sum += pv;
                }
#pragma unroll
                for (int off = 1; off < 16; off <<= 1) sum += __shfl_xor(sum, off);
                rinv[m2][r] = 1.f / sum;
            }
        __syncthreads(); // B1.5: all waves' q/k fragment reads done -> P may overlay qk

        // ---- P -> LDS (P[hh] = 8KB at QKOFF + hh*8192) ----
#pragma unroll
        for (int m2 = 0; m2 < 2; ++m2)
#pragma unroll
            for (int r = 0; r < 4; ++r) {
                int qtok = qh * 32 + m2 * 16 + lg * 4 + r;
                int sw = (qtok & 7) << 4;
#pragma unroll
                for (int nt = 0; nt < 4; ++nt) {
                    __hip_bfloat16 tb = __float2bfloat16(s[m2][nt][r]);
                    *(__hip_bfloat16*)(lds + QKOFF + hh * 8192 + qtok * 128 +
                                       (((nt * 16 + li) * 2) ^ sw)) = tb;
                }
            }
        __syncthreads(); // B2: P ready

        // ---- PV: wave = (hh, qh): m2 x n2 tiles, normalize with in-reg rinv ----
        f32x4 o[2][2] = {{(f32x4)0.f, (f32x4)0.f}, {(f32x4)0.f, (f32x4)0.f}};
#pragma unroll
        for (int kth = 0; kth < 2; ++kth) {
            short8 pa[2], vb[2];
#pragma unroll
            for (int m2 = 0; m2 < 2; ++m2) {
                int qtok = qh * 32 + m2 * 16 + li;
                pa[m2] = *(const short8*)(lds + QKOFF + hh * 8192 + qtok * 128 +
                                          ((kth * 64 + lg * 16) ^ ((li & 7) << 4)));
            }
#pragma unroll
            for (int n2 = 0; n2 < 2; ++n2) {
                int dim = hh * 32 + n2 * 16 + li;
                vb[n2] = *(const short8*)(lds + VTOFF + dim * 128 +
                                          ((kth * 64 + lg * 16) ^ ((li & 7) << 4)));
            }
#pragma unroll
            for (int m2 = 0; m2 < 2; ++m2)
#pragma unroll
                for (int n2 = 0; n2 < 2; ++n2) o[m2][n2] = MFMA(pa[m2], vb[n2], o[m2][n2]);
        }
#pragma unroll
        for (int m2 = 0; m2 < 2; ++m2)
#pragma unroll
            for (int n2 = 0; n2 < 2; ++n2)
#pragma unroll
                for (int r = 0; r < 4; ++r) o[m2][n2][r] *= rinv[m2][r];

        if (p == 0) {
            // park normalized O as packed bf16 pairs (static indices only)
#pragma unroll
            for (int m2 = 0; m2 < 2; ++m2)
#pragma unroll
                for (int n2 = 0; n2 < 2; ++n2)
#pragma unroll
                    for (int rp = 0; rp < 2; ++rp) {
                        __hip_bfloat16 blo = __float2bfloat16(o[m2][n2][2 * rp]);
                        __hip_bfloat16 bhi = __float2bfloat16(o[m2][n2][2 * rp + 1]);
                        unsigned lo = *reinterpret_cast<unsigned short*>(&blo);
                        unsigned hi = *reinterpret_cast<unsigned short*>(&bhi);
                        o1u[m2 * 4 + n2 * 2 + rp] = lo | (hi << 16);
                    }
            __syncthreads(); // B3: pass-1 P/vt reads done before pass-2 QKV overwrites
        } else {
            // write pass-2 O -> ob (cols 128..255)
#pragma unroll
            for (int m2 = 0; m2 < 2; ++m2)
#pragma unroll
                for (int n2 = 0; n2 < 2; ++n2)
#pragma unroll
                    for (int r = 0; r < 4; ++r) {
                        int tok = qh * 32 + m2 * 16 + lg * 4 + r;
                        int col = (128 + hh * 32 + n2 * 16 + li) * 2;
                        __hip_bfloat16 tb = __float2bfloat16(o[m2][n2][r]);
                        *(__hip_bfloat16*)(lds + XBOFF + tok * 512 +
                                           (col ^ ((tok & 7) << 4))) = tb;
                    }
        }
    }
    __syncthreads(); // B4: ob complete

    // ---- proj: wave wv -> out cols wv*32 .. +31 ----
    {
        f32x4 po[4][2] = {{(f32x4)0.f, (f32x4)0.f}, {(f32x4)0.f, (f32x4)0.f},
                          {(f32x4)0.f, (f32x4)0.f}, {(f32x4)0.f, (f32x4)0.f}};
#pragma unroll
        for (int kt = 0; kt < 8; ++kt) {
            short8 a[4];
#pragma unroll
            for (int mt = 0; mt < 4; ++mt)
                a[mt] = *(const short8*)(lds + XBOFF + (mt * 16 + li) * 512 +
                                         ((kt * 64 + lg * 16) ^ ((li & 7) << 4)));
#pragma unroll
            for (int n = 0; n < 2; ++n) {
                int col = wv * 32 + n * 16 + li;
                short8 bb = *(const short8*)(wp_t + col * 256 + kt * 32 + lg * 8);
#pragma unroll
                for (int mt = 0; mt < 4; ++mt) po[mt][n] = MFMA(a[mt], bb, po[mt][n]);
            }
        }
        float* op = out + (size_t)b * 16384;
#pragma unroll
        for (int n = 0; n < 2; ++n) {
            int col = wv * 32 + n * 16 + li;
            float pb = proj_b[col];
#pragma unroll
            for (int mt = 0; mt < 4; ++mt)
#pragma unroll
                for (int r = 0; r < 4; ++r)
                    op[(mt * 16 + lg * 4 + r) * 256 + col] = po[mt][n][r] + pb;
        }
    }
}

extern "C" void kernel_launch(void* const* d_in, const int* in_sizes, int n_in,
                              void* d_out, int out_size, void* d_ws, size_t ws_size,
                              hipStream_t stream) {
    const float* x      = (const float*)d_in[0];
    const float* mask   = (const float*)d_in[1];
    const float* qkv_w  = (const float*)d_in[2];
    const float* qkv_b  = (const float*)d_in[3];
    const float* proj_w = (const float*)d_in[4];
    const float* proj_b = (const float*)d_in[5];
    const float* rpb    = (const float*)d_in[6];

    __hip_bfloat16* wq_t = (__hip_bfloat16*)d_ws;          // [768][256] bf16
    __hip_bfloat16* wp_t = wq_t + 768 * 256;               // [256][256] bf16

    prep_weights<<<1024, 256, 0, stream>>>(qkv_w, proj_w, wq_t, wp_t);
    swin_fused<<<4096, 512, 0, stream>>>(x, mask, qkv_b, proj_b, rpb, wq_t, wp_t, (float*)d_out);
}